// Round 19
// baseline (259.330 us; speedup 1.0000x reference)
//
#include <hip/hip_runtime.h>
#include <hip/hip_bf16.h>
#include <cstdint>

#define NTOK 16384
#define DIM 512
#define NEXP 8
#define HID 1024
#define CAPACITY 5120

typedef __attribute__((ext_vector_type(8))) short bf16x8;
typedef __attribute__((ext_vector_type(4))) float f32x4;
typedef unsigned long long u64;

__device__ __forceinline__ unsigned short f2bf(float f) {
    unsigned u = __float_as_uint(f);
    unsigned r = (u + 0x7FFFu + ((u >> 16) & 1u)) >> 16;
    return (unsigned short)r;
}

#define GLDS16(gp, lp) __builtin_amdgcn_global_load_lds( \
    (const __attribute__((address_space(1))) void*)(gp), \
    (__attribute__((address_space(3))) void*)(lp), 16, 0, 0)

// ---------------- gating: wave per token, fp32 exact ----------------
__global__ __launch_bounds__(256) void gating_kernel(
    const float* __restrict__ x, const float* __restrict__ eps,
    const float* __restrict__ wg, const float* __restrict__ wn,
    const float* __restrict__ Wh, int2* __restrict__ rec)
{
    int w = threadIdx.x >> 6, lane = threadIdx.x & 63;
    int n = blockIdx.x * 4 + w;
    float ag[8], an[8];
#pragma unroll
    for (int e = 0; e < 8; ++e) { ag[e] = 0.f; an[e] = 0.f; }
    const float* xr = x + (size_t)n * DIM;
#pragma unroll
    for (int i = 0; i < DIM / 64; ++i) {
        int d = i * 64 + lane;
        float xv = xr[d];
        const float4* g4 = reinterpret_cast<const float4*>(wg + (size_t)d * 8);
        const float4* n4 = reinterpret_cast<const float4*>(wn + (size_t)d * 8);
        float4 a0 = g4[0], a1 = g4[1], b0 = n4[0], b1v = n4[1];
        ag[0] += xv * a0.x; ag[1] += xv * a0.y; ag[2] += xv * a0.z; ag[3] += xv * a0.w;
        ag[4] += xv * a1.x; ag[5] += xv * a1.y; ag[6] += xv * a1.z; ag[7] += xv * a1.w;
        an[0] += xv * b0.x; an[1] += xv * b0.y; an[2] += xv * b0.z; an[3] += xv * b0.w;
        an[4] += xv * b1v.x; an[5] += xv * b1v.y; an[6] += xv * b1v.z; an[7] += xv * b1v.w;
    }
#pragma unroll
    for (int off = 32; off; off >>= 1) {
#pragma unroll
        for (int e = 0; e < 8; ++e) {
            ag[e] += __shfl_xor(ag[e], off);
            an[e] += __shfl_xor(an[e], off);
        }
    }
    float noisy[8];
#pragma unroll
    for (int e = 0; e < 8; ++e) {
        float c = 0.f;
#pragma unroll
        for (int j = 0; j < 8; ++j) c += ag[j] * Wh[j * 8 + e];
        float v = an[e];
        float sp = fmaxf(v, 0.f) + log1pf(expf(-fabsf(v)));
        noisy[e] = c + eps[(size_t)n * 8 + e] * (sp + 1e-2f);
    }
    int i1 = 0; float v1 = noisy[0];
#pragma unroll
    for (int e = 1; e < 8; ++e) if (noisy[e] > v1) { v1 = noisy[e]; i1 = e; }
    int i2 = -1; float v2 = -3.4e38f;
#pragma unroll
    for (int e = 0; e < 8; ++e) if (e != i1 && noisy[e] > v2) { v2 = noisy[e]; i2 = e; }
    float ex = expf(v2 - v1);
    float g1 = 1.f / (1.f + ex);
    if (lane == 0)
        rec[n] = make_int2(i1 | (i2 << 8), __float_as_int(g1));
}

// ---- rank pass 1: per-1024-token-block local ranks + per-block expert totals ----
__global__ __launch_bounds__(1024) void scan_local(
    const int2* __restrict__ rec, unsigned* __restrict__ lrank, int* __restrict__ btot)
{
    __shared__ u64 wtot[16];
    __shared__ int wprefix[16][8];
    int tid = threadIdx.x, w = tid >> 6, lane = tid & 63;
    int n = blockIdx.x * 1024 + tid;
    int2 r = rec[n];
    int e1 = r.x & 0xFF, e2 = (r.x >> 8) & 0xFF;
    u64 m = (1ULL << (e1 * 8)) | (1ULL << (e2 * 8));
    u64 incl = m;
#pragma unroll
    for (int off = 1; off < 64; off <<= 1) {
        u64 v = __shfl_up(incl, off);
        if (lane >= off) incl += v;
    }
    if (lane == 63) wtot[w] = incl;
    __syncthreads();
    if (tid < 128) {
        int e = tid & 7, ww = tid >> 3;
        int s = 0;
        for (int j = 0; j < ww; ++j) s += (int)((wtot[j] >> (e * 8)) & 0xFF);
        wprefix[ww][e] = s;
        if (ww == 15)
            btot[blockIdx.x * 8 + e] = s + (int)((wtot[15] >> (e * 8)) & 0xFF);
    }
    __syncthreads();
    u64 excl = incl - m;
    unsigned l1 = (unsigned)(wprefix[w][e1] + (int)((excl >> (e1 * 8)) & 0xFF));
    unsigned l2 = (unsigned)(wprefix[w][e2] + (int)((excl >> (e2 * 8)) & 0xFF));
    lrank[n] = l1 | (l2 << 16);
}

// ---- rank pass 2: tiny exclusive scan of 16 block-totals per expert ----
__global__ __launch_bounds__(64) void scan_offs(
    const int* __restrict__ btot, int* __restrict__ off, int* __restrict__ counts,
    const int* __restrict__ cap_p)
{
    int e = threadIdx.x;
    if (e >= 8) return;
    int cap = *cap_p; if (cap > CAPACITY) cap = CAPACITY;
    int run = 0;
    for (int b = 0; b < 16; ++b) {
        off[b * 8 + e] = run;
        run += btot[b * 8 + e];
    }
    counts[e] = min(run, cap);
}

// ---- rank pass 3: scatter tokens into [E][CAPACITY] slots ----
__global__ __launch_bounds__(1024) void scatter_k(
    const int2* __restrict__ rec, const unsigned* __restrict__ lrank,
    const int* __restrict__ off, const int* __restrict__ cap_p,
    int* __restrict__ buf, float* __restrict__ gbuf)
{
    int tid = threadIdx.x, b = blockIdx.x;
    int n = b * 1024 + tid;
    int cap = *cap_p; if (cap > CAPACITY) cap = CAPACITY;
    int2 r = rec[n];
    int e1 = r.x & 0xFF, e2 = (r.x >> 8) & 0xFF;
    float g1 = __int_as_float(r.y), g2 = 1.f - g1;
    unsigned lr = lrank[n];
    int r1 = off[b * 8 + e1] + (int)(lr & 0xFFFF);
    int r2 = off[b * 8 + e2] + (int)(lr >> 16);
    if (r1 < cap) { buf[e1 * CAPACITY + r1] = n; gbuf[e1 * CAPACITY + r1] = g1; }
    if (r2 < cap) { buf[e2 * CAPACITY + r2] = n; gbuf[e2 * CAPACITY + r2] = g2; }
}

// ---------------- convert all of x to bf16 (xg) ----------------
__global__ __launch_bounds__(256) void cvt_x(const float* __restrict__ in,
                                             unsigned short* __restrict__ out, int n)
{
    int i = (blockIdx.x * 256 + threadIdx.x) * 8;
    if (i >= n) return;
    float4 a = *reinterpret_cast<const float4*>(in + i);
    float4 b = *reinterpret_cast<const float4*>(in + i + 4);
    int4 v;
    v.x = f2bf(a.x) | ((int)f2bf(a.y) << 16);
    v.y = f2bf(a.z) | ((int)f2bf(a.w) << 16);
    v.z = f2bf(b.x) | ((int)f2bf(b.y) << 16);
    v.w = f2bf(b.z) | ((int)f2bf(b.w) << 16);
    *reinterpret_cast<int4*>(out + i) = v;
}

// transpose+convert: in [Z][R][C] f32 -> out [Z][C][R] bf16
__global__ __launch_bounds__(256) void tcvt(const float* __restrict__ in,
                                            unsigned short* __restrict__ out, int R, int C)
{
    __shared__ float tile[32][33];
    int z = blockIdx.z;
    int c0 = blockIdx.x * 32, r0 = blockIdx.y * 32;
    int tx = threadIdx.x, ty = threadIdx.y;
    const float* inz = in + (size_t)z * R * C;
    unsigned short* outz = out + (size_t)z * R * C;
#pragma unroll
    for (int j = 0; j < 32; j += 8)
        tile[ty + j][tx] = inz[(size_t)(r0 + ty + j) * C + c0 + tx];
    __syncthreads();
#pragma unroll
    for (int j = 0; j < 32; j += 8)
        outz[(size_t)(c0 + ty + j) * R + r0 + tx] = f2bf(tile[tx][ty + j]);
}

// ====== grouped FFN GEMM: R14 inner loop + exact-fit persistent blocks ======
// Grid = 512 blocks (2/CU = measured residency -> zero tail rounds). Block b:
// e = b&7 (XCD-pinned), wb = b>>3; walks units u = wb, wb+64, ... with
// tn = wb % ntn CONSTANT per block (64 % ntn == 0), so B source offsets hoist
// out of the unit loop; only A offsets change per unit. cnt-skipped units cost
// nothing (break; units are tm-ascending). Prologue/epilogue amortized over
// ~4 (GEMM1) / ~2 (GEMM2) active units; consecutive units' epilogue stores
// overlap the next unit's first stage round (R14's proven mechanism, deeper).
// 128x128 tile, BK=64, 4 waves (2x2), 32KB single-buffer LDS, R1 swizzle
// (0 conflicts), 2-barrier drain loop - all byte-identical to R14.
// MODE 1 (GEMM1): A gathered from xg via buf, relu+b1 -> hK.
// MODE 0 (GEMM2): A linear (hK), +b2, *gate, atomicAdd scatter.
template <int MODE>
__global__ __launch_bounds__(256, 4) void ffn_gemm(
    const unsigned short* __restrict__ A, const unsigned short* __restrict__ Bt,
    const float* __restrict__ bias, unsigned short* __restrict__ Hout,
    float* __restrict__ Out, const int* __restrict__ buf,
    const float* __restrict__ gbuf, const int* __restrict__ counts,
    int Ka, int Nd)
{
    int b = blockIdx.x;
    int e = b & 7, wb = b >> 3;
    int nblk = gridDim.x >> 3;          // blocks per expert (64)
    int cnt = counts[e];
    int ntn = Nd >> 7;                  // 8 (GEMM1) or 4 (GEMM2)
    int nu = (CAPACITY >> 7) * ntn;     // units per expert
    int tn = wb % ntn;                  // constant per block

    int tid = threadIdx.x, w = tid >> 6, lane = tid & 63;
    int q = lane >> 4, rl = lane & 15;
    int ebase = e * CAPACITY;
    int wm = w >> 1, wn = w & 1;

    __shared__ __align__(16) char lds[32768];
    char* As = lds;
    char* Bs = lds + 16384;

    // staging chunk geometry + B offsets (hoisted: tn fixed)
    int srow[4], skp[4];
    unsigned boff[4];
#pragma unroll
    for (int i = 0; i < 4; ++i) {
        int p = (w * 4 + i) * 64 + lane;
        int row = p >> 3, kp = p & 7;
        int c = kp ^ (row & 7);
        srow[i] = row; skp[i] = c;
        boff[i] = (unsigned)(e * Nd + tn * 128 + row) * Ka + c * 8;
    }

    for (int u = wb; u < nu; u += nblk) {
        int tm = u / ntn;
        if (tm * 128 >= cnt) break;     // units are tm-ascending

        unsigned aoff[4];
#pragma unroll
        for (int i = 0; i < 4; ++i) {
            int slot = tm * 128 + srow[i];
            if (MODE == 1) {
                int tok = (slot < cnt) ? buf[ebase + slot] : 0;
                aoff[i] = (unsigned)tok * Ka + skp[i] * 8;
            } else {
                aoff[i] = (unsigned)(ebase + slot) * Ka + skp[i] * 8;
            }
        }

        f32x4 acc[4][4];
#pragma unroll
        for (int mi = 0; mi < 4; ++mi)
#pragma unroll
            for (int ni = 0; ni < 4; ++ni)
                acc[mi][ni] = (f32x4){0.f, 0.f, 0.f, 0.f};

        for (int k0 = 0; k0 < Ka; k0 += 64) {
#pragma unroll
            for (int i = 0; i < 4; ++i) {
                GLDS16(A + aoff[i] + k0, As + (w * 4 + i) * 1024);
                GLDS16(Bt + boff[i] + k0, Bs + (w * 4 + i) * 1024);
            }
            __syncthreads();
#pragma unroll
            for (int kk = 0; kk < 2; ++kk) {
                bf16x8 af[4], bfr[4];
#pragma unroll
                for (int mi = 0; mi < 4; ++mi) {
                    int row = wm * 64 + mi * 16 + rl;
                    int cc = (kk * 4 + q) ^ (row & 7);
                    af[mi] = *reinterpret_cast<const bf16x8*>(As + row * 128 + cc * 16);
                }
#pragma unroll
                for (int ni = 0; ni < 4; ++ni) {
                    int row = wn * 64 + ni * 16 + rl;
                    int cc = (kk * 4 + q) ^ (row & 7);
                    bfr[ni] = *reinterpret_cast<const bf16x8*>(Bs + row * 128 + cc * 16);
                }
#pragma unroll
                for (int mi = 0; mi < 4; ++mi)
#pragma unroll
                    for (int ni = 0; ni < 4; ++ni)
                        acc[mi][ni] = __builtin_amdgcn_mfma_f32_16x16x32_bf16(
                            af[mi], bfr[ni], acc[mi][ni], 0, 0, 0);
            }
            __syncthreads();
        }

        if (MODE == 1) {
#pragma unroll
            for (int ni = 0; ni < 4; ++ni) {
                int gcol = tn * 128 + wn * 64 + ni * 16 + rl;
                float bv = bias[e * Nd + gcol];
#pragma unroll
                for (int mi = 0; mi < 4; ++mi) {
#pragma unroll
                    for (int r = 0; r < 4; ++r) {
                        int grow = tm * 128 + wm * 64 + mi * 16 + q * 4 + r;
                        float v = fmaxf(acc[mi][ni][r] + bv, 0.f);
                        Hout[(size_t)(ebase + grow) * HID + gcol] = f2bf(v);
                    }
                }
            }
        } else {
#pragma unroll
            for (int ni = 0; ni < 4; ++ni) {
                int gcol = tn * 128 + wn * 64 + ni * 16 + rl;
                float bv = bias[e * Nd + gcol];
#pragma unroll
                for (int mi = 0; mi < 4; ++mi) {
#pragma unroll
                    for (int r = 0; r < 4; ++r) {
                        int grow = tm * 128 + wm * 64 + mi * 16 + q * 4 + r;
                        if (grow < cnt) {
                            int tok = buf[ebase + grow];
                            float g = gbuf[ebase + grow];
                            float v = (acc[mi][ni][r] + bv) * g;
                            atomicAdd(Out + (size_t)tok * DIM + gcol, v);
                        }
                    }
                }
            }
        }
    }
}

extern "C" void kernel_launch(void* const* d_in, const int* in_sizes, int n_in,
                              void* d_out, int out_size, void* d_ws, size_t ws_size,
                              hipStream_t stream)
{
    const float* x   = (const float*)d_in[0];
    const float* eps = (const float*)d_in[1];
    const float* wg  = (const float*)d_in[2];
    const float* wn  = (const float*)d_in[3];
    const float* Wh  = (const float*)d_in[4];
    const float* W1  = (const float*)d_in[5];
    const float* b1  = (const float*)d_in[6];
    const float* W2  = (const float*)d_in[7];
    const float* b2  = (const float*)d_in[8];
    const int* capp  = (const int*)d_in[10];

    char* ws = (char*)d_ws;
    unsigned short* xg   = (unsigned short*)(ws);              // 16,777,216  bf16 x [16384][512]
    unsigned short* w1t  = (unsigned short*)(ws + 41943040);   // 8,388,608   [E][HID][DIM]
    unsigned short* w2t  = (unsigned short*)(ws + 50331648);   // 8,388,608   [E][DIM][HID]
    unsigned short* hK   = (unsigned short*)(ws + 58720256);   // 83,886,080  h [40960][1024]
    int*      buf    = (int*)     (ws + 142606336);            // 163,840
    float*    gbuf   = (float*)   (ws + 142770176);            // 163,840
    int2*     rec    = (int2*)    (ws + 142934016);            // 131,072
    unsigned* lrank  = (unsigned*)(ws + 143065088);            // 65,536
    int*      btot   = (int*)     (ws + 143130624);            // 512
    int*      off    = (int*)     (ws + 143131136);            // 512
    int*      counts = (int*)     (ws + 143131648);            // 32

    float* out = (float*)d_out;
    hipMemsetAsync(out, 0, (size_t)out_size * sizeof(float), stream);

    gating_kernel<<<NTOK / 4, 256, 0, stream>>>(x, eps, wg, wn, Wh, rec);
    scan_local<<<16, 1024, 0, stream>>>(rec, lrank, btot);
    scan_offs<<<1, 64, 0, stream>>>(btot, off, counts, capp);
    scatter_k<<<16, 1024, 0, stream>>>(rec, lrank, off, capp, buf, gbuf);
    cvt_x<<<NTOK * DIM / 8 / 256, 256, 0, stream>>>(x, xg, NTOK * DIM);
    tcvt<<<dim3(HID / 32, DIM / 32, NEXP), dim3(32, 8), 0, stream>>>(W1, w1t, DIM, HID);
    tcvt<<<dim3(DIM / 32, HID / 32, NEXP), dim3(32, 8), 0, stream>>>(W2, w2t, HID, DIM);

    ffn_gemm<1><<<512, 256, 0, stream>>>(
        xg, w1t, b1, hK, nullptr, buf, gbuf, counts, DIM, HID);
    ffn_gemm<0><<<512, 256, 0, stream>>>(
        hK, w2t, b2, nullptr, out, buf, gbuf, counts, HID, DIM);
}

// Round 20
// 221.319 us; speedup vs baseline: 1.1717x; 1.1717x over previous
//
#include <hip/hip_runtime.h>
#include <hip/hip_bf16.h>
#include <cstdint>

#define NTOK 16384
#define DIM 512
#define NEXP 8
#define HID 1024
#define CAPACITY 5120

typedef __attribute__((ext_vector_type(8))) short bf16x8;
typedef __attribute__((ext_vector_type(4))) float f32x4;
typedef unsigned long long u64;

__device__ __forceinline__ unsigned short f2bf(float f) {
    unsigned u = __float_as_uint(f);
    unsigned r = (u + 0x7FFFu + ((u >> 16) & 1u)) >> 16;
    return (unsigned short)r;
}

#define GLDS16(gp, lp) __builtin_amdgcn_global_load_lds( \
    (const __attribute__((address_space(1))) void*)(gp), \
    (__attribute__((address_space(3))) void*)(lp), 16, 0, 0)

// ---------------- gating: wave per token, fp32 exact ----------------
__global__ __launch_bounds__(256) void gating_kernel(
    const float* __restrict__ x, const float* __restrict__ eps,
    const float* __restrict__ wg, const float* __restrict__ wn,
    const float* __restrict__ Wh, int2* __restrict__ rec)
{
    int w = threadIdx.x >> 6, lane = threadIdx.x & 63;
    int n = blockIdx.x * 4 + w;
    float ag[8], an[8];
#pragma unroll
    for (int e = 0; e < 8; ++e) { ag[e] = 0.f; an[e] = 0.f; }
    const float* xr = x + (size_t)n * DIM;
#pragma unroll
    for (int i = 0; i < DIM / 64; ++i) {
        int d = i * 64 + lane;
        float xv = xr[d];
        const float4* g4 = reinterpret_cast<const float4*>(wg + (size_t)d * 8);
        const float4* n4 = reinterpret_cast<const float4*>(wn + (size_t)d * 8);
        float4 a0 = g4[0], a1 = g4[1], b0 = n4[0], b1v = n4[1];
        ag[0] += xv * a0.x; ag[1] += xv * a0.y; ag[2] += xv * a0.z; ag[3] += xv * a0.w;
        ag[4] += xv * a1.x; ag[5] += xv * a1.y; ag[6] += xv * a1.z; ag[7] += xv * a1.w;
        an[0] += xv * b0.x; an[1] += xv * b0.y; an[2] += xv * b0.z; an[3] += xv * b0.w;
        an[4] += xv * b1v.x; an[5] += xv * b1v.y; an[6] += xv * b1v.z; an[7] += xv * b1v.w;
    }
#pragma unroll
    for (int off = 32; off; off >>= 1) {
#pragma unroll
        for (int e = 0; e < 8; ++e) {
            ag[e] += __shfl_xor(ag[e], off);
            an[e] += __shfl_xor(an[e], off);
        }
    }
    float noisy[8];
#pragma unroll
    for (int e = 0; e < 8; ++e) {
        float c = 0.f;
#pragma unroll
        for (int j = 0; j < 8; ++j) c += ag[j] * Wh[j * 8 + e];
        float v = an[e];
        float sp = fmaxf(v, 0.f) + log1pf(expf(-fabsf(v)));
        noisy[e] = c + eps[(size_t)n * 8 + e] * (sp + 1e-2f);
    }
    int i1 = 0; float v1 = noisy[0];
#pragma unroll
    for (int e = 1; e < 8; ++e) if (noisy[e] > v1) { v1 = noisy[e]; i1 = e; }
    int i2 = -1; float v2 = -3.4e38f;
#pragma unroll
    for (int e = 0; e < 8; ++e) if (e != i1 && noisy[e] > v2) { v2 = noisy[e]; i2 = e; }
    float ex = expf(v2 - v1);
    float g1 = 1.f / (1.f + ex);
    if (lane == 0)
        rec[n] = make_int2(i1 | (i2 << 8), __float_as_int(g1));
}

// ---- rank pass 1: per-1024-token-block local ranks + per-block expert totals ----
__global__ __launch_bounds__(1024) void scan_local(
    const int2* __restrict__ rec, unsigned* __restrict__ lrank, int* __restrict__ btot)
{
    __shared__ u64 wtot[16];
    __shared__ int wprefix[16][8];
    int tid = threadIdx.x, w = tid >> 6, lane = tid & 63;
    int n = blockIdx.x * 1024 + tid;
    int2 r = rec[n];
    int e1 = r.x & 0xFF, e2 = (r.x >> 8) & 0xFF;
    u64 m = (1ULL << (e1 * 8)) | (1ULL << (e2 * 8));
    u64 incl = m;
#pragma unroll
    for (int off = 1; off < 64; off <<= 1) {
        u64 v = __shfl_up(incl, off);
        if (lane >= off) incl += v;
    }
    if (lane == 63) wtot[w] = incl;
    __syncthreads();
    if (tid < 128) {
        int e = tid & 7, ww = tid >> 3;
        int s = 0;
        for (int j = 0; j < ww; ++j) s += (int)((wtot[j] >> (e * 8)) & 0xFF);
        wprefix[ww][e] = s;
        if (ww == 15)
            btot[blockIdx.x * 8 + e] = s + (int)((wtot[15] >> (e * 8)) & 0xFF);
    }
    __syncthreads();
    u64 excl = incl - m;
    unsigned l1 = (unsigned)(wprefix[w][e1] + (int)((excl >> (e1 * 8)) & 0xFF));
    unsigned l2 = (unsigned)(wprefix[w][e2] + (int)((excl >> (e2 * 8)) & 0xFF));
    lrank[n] = l1 | (l2 << 16);
}

// ---- rank pass 2: tiny exclusive scan of 16 block-totals per expert ----
__global__ __launch_bounds__(64) void scan_offs(
    const int* __restrict__ btot, int* __restrict__ off, int* __restrict__ counts,
    const int* __restrict__ cap_p)
{
    int e = threadIdx.x;
    if (e >= 8) return;
    int cap = *cap_p; if (cap > CAPACITY) cap = CAPACITY;
    int run = 0;
    for (int b = 0; b < 16; ++b) {
        off[b * 8 + e] = run;
        run += btot[b * 8 + e];
    }
    counts[e] = min(run, cap);
}

// ---- rank pass 3: scatter tokens into [E][CAPACITY] slots ----
__global__ __launch_bounds__(1024) void scatter_k(
    const int2* __restrict__ rec, const unsigned* __restrict__ lrank,
    const int* __restrict__ off, const int* __restrict__ cap_p,
    int* __restrict__ buf, float* __restrict__ gbuf)
{
    int tid = threadIdx.x, b = blockIdx.x;
    int n = b * 1024 + tid;
    int cap = *cap_p; if (cap > CAPACITY) cap = CAPACITY;
    int2 r = rec[n];
    int e1 = r.x & 0xFF, e2 = (r.x >> 8) & 0xFF;
    float g1 = __int_as_float(r.y), g2 = 1.f - g1;
    unsigned lr = lrank[n];
    int r1 = off[b * 8 + e1] + (int)(lr & 0xFFFF);
    int r2 = off[b * 8 + e2] + (int)(lr >> 16);
    if (r1 < cap) { buf[e1 * CAPACITY + r1] = n; gbuf[e1 * CAPACITY + r1] = g1; }
    if (r2 < cap) { buf[e2 * CAPACITY + r2] = n; gbuf[e2 * CAPACITY + r2] = g2; }
}

// ---------------- convert all of x to bf16 (xg) ----------------
__global__ __launch_bounds__(256) void cvt_x(const float* __restrict__ in,
                                             unsigned short* __restrict__ out, int n)
{
    int i = (blockIdx.x * 256 + threadIdx.x) * 8;
    if (i >= n) return;
    float4 a = *reinterpret_cast<const float4*>(in + i);
    float4 b = *reinterpret_cast<const float4*>(in + i + 4);
    int4 v;
    v.x = f2bf(a.x) | ((int)f2bf(a.y) << 16);
    v.y = f2bf(a.z) | ((int)f2bf(a.w) << 16);
    v.z = f2bf(b.x) | ((int)f2bf(b.y) << 16);
    v.w = f2bf(b.z) | ((int)f2bf(b.w) << 16);
    *reinterpret_cast<int4*>(out + i) = v;
}

// transpose+convert: in [Z][R][C] f32 -> out [Z][C][R] bf16
__global__ __launch_bounds__(256) void tcvt(const float* __restrict__ in,
                                            unsigned short* __restrict__ out, int R, int C)
{
    __shared__ float tile[32][33];
    int z = blockIdx.z;
    int c0 = blockIdx.x * 32, r0 = blockIdx.y * 32;
    int tx = threadIdx.x, ty = threadIdx.y;
    const float* inz = in + (size_t)z * R * C;
    unsigned short* outz = out + (size_t)z * R * C;
#pragma unroll
    for (int j = 0; j < 32; j += 8)
        tile[ty + j][tx] = inz[(size_t)(r0 + ty + j) * C + c0 + tx];
    __syncthreads();
#pragma unroll
    for (int j = 0; j < 32; j += 8)
        outz[(size_t)(c0 + ty + j) * R + r0 + tx] = f2bf(tile[tx][ty + j]);
}

// -------- grouped FFN GEMM: R14 winner (2-tile persistent blocks) --------
// 128x128 tile, BK=64, 4 waves (2x2), 32KB single-buffer LDS, XOR-swizzled
// staging (0 conflicts). Each block processes TWO consecutive tm-tiles at the
// same (e, tn): one prologue per pair (B offsets shared), and tile-1's epilogue
// stores overlap tile-2's first stage round (drained together at its first
// barrier) - amortizes the short-K prologue/epilogue cost that caps this shape.
// XCD remap: e = flat&7, tn fastest. MODE 1 (GEMM1): A gathered from xg via
// buf, relu+b1 -> hK. MODE 0 (GEMM2): A linear (hK), +b2, *gate, atomicAdd.
template <int MODE>
__global__ __launch_bounds__(256, 4) void ffn_gemm(
    const unsigned short* __restrict__ A, const unsigned short* __restrict__ Bt,
    const float* __restrict__ bias, unsigned short* __restrict__ Hout,
    float* __restrict__ Out, const int* __restrict__ buf,
    const float* __restrict__ gbuf, const int* __restrict__ counts,
    int Ka, int Nd)
{
    int flat = blockIdx.x + gridDim.x * (blockIdx.y + gridDim.y * blockIdx.z);
    int e  = flat & 7;
    int rr = flat >> 3;
    int tn = rr % gridDim.y;
    int tmb = rr / gridDim.y;      // tile-pair index: tiles 2*tmb, 2*tmb+1

    int cnt = counts[e];
    if (tmb * 256 >= cnt) return;
    int tid = threadIdx.x, w = tid >> 6, lane = tid & 63;
    int q = lane >> 4, rl = lane & 15;
    int ebase = e * CAPACITY;
    int wm = w >> 1, wn = w & 1;

    __shared__ __align__(16) char lds[32768];
    char* As = lds;
    char* Bs = lds + 16384;

    // B staging source offsets (elements, k excluded) - shared by both tiles
    unsigned boff[4];
    int srow[4], skp[4];
#pragma unroll
    for (int i = 0; i < 4; ++i) {
        int p = (w * 4 + i) * 64 + lane;
        int row = p >> 3, kp = p & 7;
        int c = kp ^ (row & 7);
        srow[i] = row; skp[i] = c;
        boff[i] = (unsigned)(e * Nd + tn * 128 + row) * Ka + c * 8;
    }

    for (int it = 0; it < 2; ++it) {
        int tm = tmb * 2 + it;
        if (tm * 128 >= cnt) break;

        // A staging source offsets for this tile
        unsigned aoff[4];
#pragma unroll
        for (int i = 0; i < 4; ++i) {
            int slot = tm * 128 + srow[i];
            if (MODE == 1) {
                int tok = (slot < cnt) ? buf[ebase + slot] : 0;
                aoff[i] = (unsigned)tok * Ka + skp[i] * 8;
            } else {
                aoff[i] = (unsigned)(ebase + slot) * Ka + skp[i] * 8;
            }
        }

        f32x4 acc[4][4];
#pragma unroll
        for (int mi = 0; mi < 4; ++mi)
#pragma unroll
            for (int ni = 0; ni < 4; ++ni)
                acc[mi][ni] = (f32x4){0.f, 0.f, 0.f, 0.f};

        for (int k0 = 0; k0 < Ka; k0 += 64) {
#pragma unroll
            for (int i = 0; i < 4; ++i) {
                GLDS16(A + aoff[i] + k0, As + (w * 4 + i) * 1024);
                GLDS16(Bt + boff[i] + k0, Bs + (w * 4 + i) * 1024);
            }
            __syncthreads();
#pragma unroll
            for (int kk = 0; kk < 2; ++kk) {
                bf16x8 af[4], bfr[4];
#pragma unroll
                for (int mi = 0; mi < 4; ++mi) {
                    int row = wm * 64 + mi * 16 + rl;
                    int cc = (kk * 4 + q) ^ (row & 7);
                    af[mi] = *reinterpret_cast<const bf16x8*>(As + row * 128 + cc * 16);
                }
#pragma unroll
                for (int ni = 0; ni < 4; ++ni) {
                    int row = wn * 64 + ni * 16 + rl;
                    int cc = (kk * 4 + q) ^ (row & 7);
                    bfr[ni] = *reinterpret_cast<const bf16x8*>(Bs + row * 128 + cc * 16);
                }
#pragma unroll
                for (int mi = 0; mi < 4; ++mi)
#pragma unroll
                    for (int ni = 0; ni < 4; ++ni)
                        acc[mi][ni] = __builtin_amdgcn_mfma_f32_16x16x32_bf16(
                            af[mi], bfr[ni], acc[mi][ni], 0, 0, 0);
            }
            __syncthreads();
        }

        if (MODE == 1) {
#pragma unroll
            for (int ni = 0; ni < 4; ++ni) {
                int gcol = tn * 128 + wn * 64 + ni * 16 + rl;
                float bv = bias[e * Nd + gcol];
#pragma unroll
                for (int mi = 0; mi < 4; ++mi) {
#pragma unroll
                    for (int r = 0; r < 4; ++r) {
                        int grow = tm * 128 + wm * 64 + mi * 16 + q * 4 + r;
                        float v = fmaxf(acc[mi][ni][r] + bv, 0.f);
                        Hout[(size_t)(ebase + grow) * HID + gcol] = f2bf(v);
                    }
                }
            }
        } else {
#pragma unroll
            for (int ni = 0; ni < 4; ++ni) {
                int gcol = tn * 128 + wn * 64 + ni * 16 + rl;
                float bv = bias[e * Nd + gcol];
#pragma unroll
                for (int mi = 0; mi < 4; ++mi) {
#pragma unroll
                    for (int r = 0; r < 4; ++r) {
                        int grow = tm * 128 + wm * 64 + mi * 16 + q * 4 + r;
                        if (grow < cnt) {
                            int tok = buf[ebase + grow];
                            float g = gbuf[ebase + grow];
                            float v = (acc[mi][ni][r] + bv) * g;
                            atomicAdd(Out + (size_t)tok * DIM + gcol, v);
                        }
                    }
                }
            }
        }
    }
}

extern "C" void kernel_launch(void* const* d_in, const int* in_sizes, int n_in,
                              void* d_out, int out_size, void* d_ws, size_t ws_size,
                              hipStream_t stream)
{
    const float* x   = (const float*)d_in[0];
    const float* eps = (const float*)d_in[1];
    const float* wg  = (const float*)d_in[2];
    const float* wn  = (const float*)d_in[3];
    const float* Wh  = (const float*)d_in[4];
    const float* W1  = (const float*)d_in[5];
    const float* b1  = (const float*)d_in[6];
    const float* W2  = (const float*)d_in[7];
    const float* b2  = (const float*)d_in[8];
    const int* capp  = (const int*)d_in[10];

    char* ws = (char*)d_ws;
    unsigned short* xg   = (unsigned short*)(ws);              // 16,777,216  bf16 x [16384][512]
    unsigned short* w1t  = (unsigned short*)(ws + 41943040);   // 8,388,608   [E][HID][DIM]
    unsigned short* w2t  = (unsigned short*)(ws + 50331648);   // 8,388,608   [E][DIM][HID]
    unsigned short* hK   = (unsigned short*)(ws + 58720256);   // 83,886,080  h [40960][1024]
    int*      buf    = (int*)     (ws + 142606336);            // 163,840
    float*    gbuf   = (float*)   (ws + 142770176);            // 163,840
    int2*     rec    = (int2*)    (ws + 142934016);            // 131,072
    unsigned* lrank  = (unsigned*)(ws + 143065088);            // 65,536
    int*      btot   = (int*)     (ws + 143130624);            // 512
    int*      off    = (int*)     (ws + 143131136);            // 512
    int*      counts = (int*)     (ws + 143131648);            // 32

    float* out = (float*)d_out;
    hipMemsetAsync(out, 0, (size_t)out_size * sizeof(float), stream);

    gating_kernel<<<NTOK / 4, 256, 0, stream>>>(x, eps, wg, wn, Wh, rec);
    scan_local<<<16, 1024, 0, stream>>>(rec, lrank, btot);
    scan_offs<<<1, 64, 0, stream>>>(btot, off, counts, capp);
    scatter_k<<<16, 1024, 0, stream>>>(rec, lrank, off, capp, buf, gbuf);
    cvt_x<<<NTOK * DIM / 8 / 256, 256, 0, stream>>>(x, xg, NTOK * DIM);
    tcvt<<<dim3(HID / 32, DIM / 32, NEXP), dim3(32, 8), 0, stream>>>(W1, w1t, DIM, HID);
    tcvt<<<dim3(DIM / 32, HID / 32, NEXP), dim3(32, 8), 0, stream>>>(W2, w2t, HID, DIM);

    ffn_gemm<1><<<dim3(CAPACITY / 256, HID / 128, NEXP), 256, 0, stream>>>(
        xg, w1t, b1, hK, nullptr, buf, gbuf, counts, DIM, HID);
    ffn_gemm<0><<<dim3(CAPACITY / 256, DIM / 128, NEXP), 256, 0, stream>>>(
        hK, w2t, b2, nullptr, out, buf, gbuf, counts, HID, DIM);
}